// Round 10
// baseline (684.852 us; speedup 1.0000x reference)
//
#include <hip/hip_runtime.h>

typedef unsigned int u32;
typedef unsigned short u16;
typedef __attribute__((ext_vector_type(8))) short short8;
typedef __attribute__((ext_vector_type(4))) float f32x4;

#define DD 128
#define RREL 8
#define AMW 1024    // Am row width (8 rel * 128)
#define NKT 9       // k-tiles: [root | W0..W7], 128 k each
#define SCAN_CHUNK 4096
#define NCHUNK 25000  // nodes per layer-chunk (Am chunk = 51.2 MB, L3-resident)

static __device__ __forceinline__ u16 f2bf(float f) {
  u32 u = __builtin_bit_cast(u32, f);
  u32 r = (u + 0x7fffu + ((u >> 16) & 1u)) >> 16;
  return (u16)r;
}
static __device__ __forceinline__ float bflo(u32 v) { return __builtin_bit_cast(float, v << 16); }
static __device__ __forceinline__ float bfhi(u32 v) { return __builtin_bit_cast(float, v & 0xffff0000u); }

// ---- build pre-swizzled transposed weights for linear global_load_lds staging.
__global__ __launch_bounds__(256) void k_convw(const float* __restrict__ W,
                                               const float* __restrict__ root,
                                               uint4* __restrict__ wt) {
  int t = blockIdx.x * 256 + threadIdx.x;
  if (t >= 2 * NKT * 2048) return;
  int l = t / (NKT * 2048);
  int rem = t - l * (NKT * 2048);
  int kt = rem >> 11;
  int pos = rem & 2047;
  int col = pos >> 4;
  int cbx = pos & 15;
  int cb = cbx ^ (col & 7);
  int k0 = kt * DD + cb * 8;
  u16 vals[8];
#pragma unroll
  for (int i = 0; i < 8; ++i) {
    int k = k0 + i;
    float v;
    if (k < DD) {
      v = root[(size_t)l * DD * DD + k * DD + col];
    } else {
      int km = k - DD;
      v = W[((size_t)l * RREL + (km >> 7)) * DD * DD + (size_t)(km & 127) * DD + col];
    }
    vals[i] = f2bf(v);
  }
  wt[t] = *(uint4*)vals;
}

// ---- h0 = bf16(emb[x]) dense [N][128]
__global__ __launch_bounds__(256) void k_gather(const int* __restrict__ x,
                                                const float* __restrict__ emb,
                                                u16* __restrict__ h0, int N) {
  int t = blockIdx.x * 256 + threadIdx.x;
  if (t >= N * 16) return;
  int node = t >> 4, part = t & 15;
  const float4* e4 = (const float4*)(emb + (size_t)x[node] * DD + part * 8);
  float4 f0 = e4[0], f1 = e4[1];
  uint4 u;
  u.x = (u32)f2bf(f0.x) | ((u32)f2bf(f0.y) << 16);
  u.y = (u32)f2bf(f0.z) | ((u32)f2bf(f0.w) << 16);
  u.z = (u32)f2bf(f1.x) | ((u32)f2bf(f1.y) << 16);
  u.w = (u32)f2bf(f1.z) | ((u32)f2bf(f1.w) << 16);
  *(uint4*)(h0 + (size_t)node * DD + part * 8) = u;
}

// ---- histogram over segments seg = dst*8 + etype, 1 edge/thread (TLP > ILP for atomics)
__global__ __launch_bounds__(256) void k_hist(const int* __restrict__ ei,
                                              const int* __restrict__ et,
                                              int* __restrict__ cnt, int E) {
  int e = blockIdx.x * 256 + threadIdx.x;
  if (e >= E) return;
  int dst = ei[E + e];
  atomicAdd(&cnt[dst * 8 + et[e]], 1);
}

__global__ __launch_bounds__(256) void k_scan_reduce(const int* __restrict__ cnt,
                                                     int* __restrict__ blksum, int nseg) {
  __shared__ int s[256];
  int b = blockIdx.x, t = threadIdx.x;
  int base = b * SCAN_CHUNK;
  int sum = 0;
  for (int i = 0; i < 16; ++i) {
    int idx = base + i * 256 + t;
    if (idx < nseg) sum += cnt[idx];
  }
  s[t] = sum;
  __syncthreads();
  for (int st = 128; st > 0; st >>= 1) {
    if (t < st) s[t] += s[t + st];
    __syncthreads();
  }
  if (t == 0) blksum[b] = s[0];
}

__global__ void k_scan_top(int* __restrict__ blksum, int nblk, int* __restrict__ off,
                           int nseg, int E) {
  if (threadIdx.x == 0 && blockIdx.x == 0) {
    int run = 0;
    for (int b = 0; b < nblk; ++b) { int v = blksum[b]; blksum[b] = run; run += v; }
    off[nseg] = E;
  }
}

// writes off AND fill (scatter cursor) -> no separate memcpy
__global__ __launch_bounds__(256) void k_scan_write(const int* __restrict__ cnt,
                                                    const int* __restrict__ blksum,
                                                    int* __restrict__ off,
                                                    int* __restrict__ fill, int nseg) {
  __shared__ int s[256];
  int b = blockIdx.x, t = threadIdx.x;
  int base = b * SCAN_CHUNK + t * 16;
  int v[16];
  int sum = 0;
#pragma unroll
  for (int i = 0; i < 16; ++i) {
    int idx = base + i;
    v[i] = (idx < nseg) ? cnt[idx] : 0;
    sum += v[i];
  }
  s[t] = sum;
  __syncthreads();
  for (int st = 1; st < 256; st <<= 1) {
    int add = (t >= st) ? s[t - st] : 0;
    __syncthreads();
    s[t] += add;
    __syncthreads();
  }
  int run = blksum[b] + s[t] - sum;
#pragma unroll
  for (int i = 0; i < 16; ++i) {
    int idx = base + i;
    if (idx < nseg) { off[idx] = run; fill[idx] = run; }
    run += v[i];
  }
}

// ---- scatter: pos = atomicAdd(&fill[seg],1). 1 edge/thread (measured fastest: TLP).
__global__ __launch_bounds__(256) void k_scatter(const int* __restrict__ ei,
                                                 const int* __restrict__ et,
                                                 int* __restrict__ fill,
                                                 int* __restrict__ sorted, int E) {
  int e = blockIdx.x * 256 + threadIdx.x;
  if (e >= E) return;
  int src = ei[e], dst = ei[E + e];
  int pos = atomicAdd(&fill[dst * 8 + et[e]], 1);
  sorted[pos] = src;
}

static __device__ __forceinline__ void add8(float* a, uint4 v) {
  a[0] += bflo(v.x); a[1] += bfhi(v.x);
  a[2] += bflo(v.y); a[3] += bfhi(v.y);
  a[4] += bflo(v.z); a[5] += bfhi(v.z);
  a[6] += bflo(v.w); a[7] += bfhi(v.w);
}

// ---- aggregation over a node chunk [dst0, dend): each 8-lane group walks ONE dst's
// contiguous 8-relation edge span, flushing each relation's mean at its boundary.
// Gathers read dense h [N][128] (L3-resident); writes Am chunk (recycled, L3-hot).
__global__ __launch_bounds__(256) void k_agg(const int* __restrict__ off,
                                             const int* __restrict__ sorted,
                                             const u16* __restrict__ hin,
                                             u16* __restrict__ am, int dst0, int dend,
                                             int E) {
  int wave = threadIdx.x >> 6, lane = threadIdx.x & 63;
  int grp = lane >> 3, oct = lane & 7;
  int dst = dst0 + blockIdx.x * 32 + wave * 8 + grp;
  if (dst >= dend) return;
  int4 b0 = *(const int4*)(off + dst * 8);
  int4 b1 = *(const int4*)(off + dst * 8 + 4);
  int je = off[dst * 8 + 8];
  int cs = b0.x;
  int e1 = b0.y, e2 = b0.z, e3 = b0.w, e4 = b1.x, e5 = b1.y, e6 = b1.z, e7 = b1.w, e8 = je;
  u16* ambase = am + (size_t)(dst - dst0) * AMW + oct * 16;
  float a[16];
#pragma unroll
  for (int i = 0; i < 16; ++i) a[i] = 0.f;
  int j = cs;
  int r = 0;
  int lastidx = (E > 0) ? E - 1 : 0;
  while (true) {
    while (r < 8 && j >= e1) {
      int cnt = e1 - cs;
      float norm = (cnt > 0) ? 1.0f / (float)cnt : 0.f;
      uint4 w0, w1;
      w0.x = (u32)f2bf(a[0] * norm) | ((u32)f2bf(a[1] * norm) << 16);
      w0.y = (u32)f2bf(a[2] * norm) | ((u32)f2bf(a[3] * norm) << 16);
      w0.z = (u32)f2bf(a[4] * norm) | ((u32)f2bf(a[5] * norm) << 16);
      w0.w = (u32)f2bf(a[6] * norm) | ((u32)f2bf(a[7] * norm) << 16);
      w1.x = (u32)f2bf(a[8] * norm) | ((u32)f2bf(a[9] * norm) << 16);
      w1.y = (u32)f2bf(a[10] * norm) | ((u32)f2bf(a[11] * norm) << 16);
      w1.z = (u32)f2bf(a[12] * norm) | ((u32)f2bf(a[13] * norm) << 16);
      w1.w = (u32)f2bf(a[14] * norm) | ((u32)f2bf(a[15] * norm) << 16);
      uint4* outp = (uint4*)(ambase + (size_t)r * DD);
      outp[0] = w0;
      outp[1] = w1;
#pragma unroll
      for (int i = 0; i < 16; ++i) a[i] = 0.f;
      cs = e1;
      e1 = e2; e2 = e3; e3 = e4; e4 = e5; e5 = e6; e6 = e7; e7 = e8;
      ++r;
    }
    if (r >= 8) break;
    int j1 = j + 1;
    bool two = (j1 < e1);
    int s0 = sorted[j];
    int s1 = sorted[two ? j1 : lastidx];
    const uint4* p0 = (const uint4*)(hin + (size_t)s0 * DD + oct * 16);
    const uint4* p1 = (const uint4*)(hin + (size_t)s1 * DD + oct * 16);
    uint4 v0 = p0[0], v0b = p0[1];
    uint4 v1 = p1[0], v1b = p1[1];
    if (!two) {
      v1.x = v1.y = v1.z = v1.w = 0u;
      v1b.x = v1b.y = v1b.z = v1b.w = 0u;
    }
    add8(a, v0); add8(a + 8, v0b);
    add8(a, v1); add8(a + 8, v1b);
    j += two ? 2 : 1;
  }
}

// ---- fused GEMM over rows [row0, row1): out[row] = relu([h[row]|Am[row-row0]] @ Wcat + bias)
// 128 rows/block, 8 waves. B k-tiles (32KB) double-buffered in LDS via global_load_lds
// (wt pre-swizzled). Am chunk is L3-hot (just written by k_agg for the same rows).
template <bool LAST>
__global__ __launch_bounds__(512) void k_gemm(const u16* __restrict__ h,
                                              const u16* __restrict__ am,
                                              const uint4* __restrict__ wt,
                                              const float* __restrict__ bias,
                                              u16* __restrict__ hout,
                                              float* __restrict__ dout, int row0,
                                              int row1) {
  __shared__ uint4 ldsB[2][2048];  // 2 x 32KB
  int tid = threadIdx.x, wave = tid >> 6, lane = tid & 63;
  int rowbase = row0 + blockIdx.x * 128 + wave * 16;
  int arow = rowbase + (lane & 15);
  int arc = arow < row1 ? arow : row1 - 1;
  int klane = (lane >> 4) << 3;
  f32x4 acc[8];
#pragma unroll
  for (int c = 0; c < 8; ++c) acc[c] = (f32x4)0.f;

#define STAGE(KT, BUF)                                                                   \
  do {                                                                                   \
    const uint4* gsrc = wt + (size_t)(KT) * 2048;                                        \
    _Pragma("unroll") for (int i_ = 0; i_ < 4; ++i_) {                                   \
      int cid_ = i_ * 512 + tid;                                                         \
      __builtin_amdgcn_global_load_lds(                                                  \
          (const __attribute__((address_space(1))) uint4*)(gsrc + cid_),                 \
          (__attribute__((address_space(3))) uint4*)&ldsB[BUF][cid_], 16, 0, 0);         \
    }                                                                                    \
  } while (0)

  STAGE(0, 0);
  for (int kt = 0; kt < NKT; ++kt) {
    int cur = kt & 1;
    __syncthreads();  // drains vmcnt -> buf[cur] staged; syncs reuse of buf[cur^1]
    if (kt + 1 < NKT) STAGE(kt + 1, cur ^ 1);
    const u16* abase = (kt == 0) ? (h + (size_t)arc * DD)
                                 : (am + (size_t)(arc - row0) * AMW + (kt - 1) * DD);
#pragma unroll
    for (int kc = 0; kc < 4; ++kc) {
      short8 a = *(const short8*)(abase + kc * 32 + klane);
      int chunk = kc * 4 + (lane >> 4);
#pragma unroll
      for (int c = 0; c < 8; ++c) {
        int col = c * 16 + (lane & 15);
        const short8* bp = (const short8*)&ldsB[cur][col * 16 + (chunk ^ (col & 7))];
        acc[c] = __builtin_amdgcn_mfma_f32_16x16x32_bf16(a, *bp, acc[c], 0, 0, 0);
      }
    }
  }
#undef STAGE

  int crow0 = rowbase + ((lane >> 4) << 2);
  int ccol = lane & 15;
#pragma unroll
  for (int c = 0; c < 8; ++c) {
    int col = c * 16 + ccol;
    float bv = bias[col];
#pragma unroll
    for (int i = 0; i < 4; ++i) {
      int row = crow0 + i;
      if (row < row1) {
        float v = fmaxf(acc[c][i] + bv, 0.f);
        if (LAST) dout[(size_t)row * DD + col] = v;
        else hout[(size_t)row * DD + col] = f2bf(v);
      }
    }
  }
}

extern "C" void kernel_launch(void* const* d_in, const int* in_sizes, int n_in,
                              void* d_out, int out_size, void* d_ws, size_t ws_size,
                              hipStream_t stream) {
  const int* x = (const int*)d_in[0];
  const int* ei = (const int*)d_in[1];
  const int* et = (const int*)d_in[2];
  const float* emb = (const float*)d_in[3];
  const float* W = (const float*)d_in[4];
  const float* root = (const float*)d_in[5];
  const float* bias = (const float*)d_in[6];

  const int N = in_sizes[0];
  const int E = in_sizes[2];
  const int NSEG = N * RREL;

  // workspace ~119 MB: metadata 16.6 + h0 25.6 + h1 25.6 + Am chunk 51.2
  size_t o = 0;
  auto al = [&](size_t b) { size_t r = o; o = (o + b + 255) & ~(size_t)255; return r; };
  size_t off_o = al(((size_t)NSEG + 1) * 4);
  size_t cnt_o = al((size_t)NSEG * 4);
  size_t fill_o = al((size_t)NSEG * 4);
  size_t sorted_o = al((size_t)E * 4);
  size_t blk_o = al(4096);
  size_t wt_o = al((size_t)2 * NKT * 2048 * 16);
  size_t h0_o = al((size_t)N * DD * 2);
  size_t h1_o = al((size_t)N * DD * 2);
  size_t am_o = al((size_t)NCHUNK * AMW * 2);
  (void)am_o;

  char* ws = (char*)d_ws;
  int* off = (int*)(ws + off_o);
  int* cnt = (int*)(ws + cnt_o);
  int* fill = (int*)(ws + fill_o);
  int* sorted = (int*)(ws + sorted_o);
  int* blks = (int*)(ws + blk_o);
  uint4* wt = (uint4*)(ws + wt_o);
  u16* h0 = (u16*)(ws + h0_o);
  u16* h1 = (u16*)(ws + h1_o);
  u16* am = (u16*)(ws + am_o);
  float* outf = (float*)d_out;

  // ---- prep
  k_convw<<<(2 * NKT * 2048 + 255) / 256, 256, 0, stream>>>(W, root, wt);
  k_gather<<<(N * 16 + 255) / 256, 256, 0, stream>>>(x, emb, h0, N);
  hipMemsetAsync(cnt, 0, (size_t)NSEG * 4, stream);
  k_hist<<<(E + 255) / 256, 256, 0, stream>>>(ei, et, cnt, E);
  int nblk = (NSEG + SCAN_CHUNK - 1) / SCAN_CHUNK;
  k_scan_reduce<<<nblk, 256, 0, stream>>>(cnt, blks, NSEG);
  k_scan_top<<<1, 64, 0, stream>>>(blks, nblk, off, NSEG, E);
  k_scan_write<<<nblk, 256, 0, stream>>>(cnt, blks, off, fill, NSEG);
  k_scatter<<<(E + 255) / 256, 256, 0, stream>>>(ei, et, fill, sorted, E);

  // ---- layers, chunked so the recycled Am buffer stays L3-resident between agg and gemm
  for (int l = 0; l < 2; ++l) {
    const u16* hin = l ? h1 : h0;
    for (int c0 = 0; c0 < N; c0 += NCHUNK) {
      int c1 = c0 + NCHUNK < N ? c0 + NCHUNK : N;
      int rows = c1 - c0;
      k_agg<<<(rows + 31) / 32, 256, 0, stream>>>(off, sorted, hin, am, c0, c1, E);
      int gx = (rows + 127) / 128;
      if (l == 0)
        k_gemm<false><<<gx, 512, 0, stream>>>(hin, am, wt, bias, h1, nullptr, c0, c1);
      else
        k_gemm<true><<<gx, 512, 0, stream>>>(hin, am, wt + (size_t)NKT * 2048, bias + DD,
                                             nullptr, outf, c0, c1);
    }
  }
}

// Round 11
// 571.201 us; speedup vs baseline: 1.1990x; 1.1990x over previous
//
#include <hip/hip_runtime.h>

typedef unsigned int u32;
typedef unsigned short u16;
typedef __attribute__((ext_vector_type(8))) short short8;
typedef __attribute__((ext_vector_type(4))) float f32x4;

#define DD 128
#define RREL 8
#define AMW 1024   // Am row width (8 rel * 128)
#define NKT 9      // k-tiles: [root | W0..W7], 128 k each
#define SCAN_CHUNK 4096
#define EPB 1024   // edges per partition block

static __device__ __forceinline__ u16 f2bf(float f) {
  u32 u = __builtin_bit_cast(u32, f);
  u32 r = (u + 0x7fffu + ((u >> 16) & 1u)) >> 16;
  return (u16)r;
}
static __device__ __forceinline__ float bflo(u32 v) { return __builtin_bit_cast(float, v << 16); }
static __device__ __forceinline__ float bfhi(u32 v) { return __builtin_bit_cast(float, v & 0xffff0000u); }

// ---- build pre-swizzled transposed weights for linear global_load_lds staging.
__global__ __launch_bounds__(256) void k_convw(const float* __restrict__ W,
                                               const float* __restrict__ root,
                                               uint4* __restrict__ wt) {
  int t = blockIdx.x * 256 + threadIdx.x;
  if (t >= 2 * NKT * 2048) return;
  int l = t / (NKT * 2048);
  int rem = t - l * (NKT * 2048);
  int kt = rem >> 11;
  int pos = rem & 2047;
  int col = pos >> 4;
  int cbx = pos & 15;
  int cb = cbx ^ (col & 7);
  int k0 = kt * DD + cb * 8;
  u16 vals[8];
#pragma unroll
  for (int i = 0; i < 8; ++i) {
    int k = k0 + i;
    float v;
    if (k < DD) {
      v = root[(size_t)l * DD * DD + k * DD + col];
    } else {
      int km = k - DD;
      v = W[((size_t)l * RREL + (km >> 7)) * DD * DD + (size_t)(km & 127) * DD + col];
    }
    vals[i] = f2bf(v);
  }
  wt[t] = *(uint4*)vals;
}

// ---- h0 = bf16(emb[x]) dense [N][128]
__global__ __launch_bounds__(256) void k_gather(const int* __restrict__ x,
                                                const float* __restrict__ emb,
                                                u16* __restrict__ h0, int N) {
  int t = blockIdx.x * 256 + threadIdx.x;
  if (t >= N * 16) return;
  int node = t >> 4, part = t & 15;
  const float4* e4 = (const float4*)(emb + (size_t)x[node] * DD + part * 8);
  float4 f0 = e4[0], f1 = e4[1];
  uint4 u;
  u.x = (u32)f2bf(f0.x) | ((u32)f2bf(f0.y) << 16);
  u.y = (u32)f2bf(f0.z) | ((u32)f2bf(f0.w) << 16);
  u.z = (u32)f2bf(f1.x) | ((u32)f2bf(f1.y) << 16);
  u.w = (u32)f2bf(f1.z) | ((u32)f2bf(f1.w) << 16);
  *(uint4*)(h0 + (size_t)node * DD + part * 8) = u;
}

// ---- per-block per-bucket counts (bucket = dst / N8), stored b-major: cnt8[b*nblk+blk]
__global__ __launch_bounds__(256) void k_cnt8(const int* __restrict__ eid,
                                              int* __restrict__ cnt8, int E, int N8,
                                              int nblk) {
  __shared__ u32 s[4];
  int blk = blockIdx.x, tid = threadIdx.x;
  if (tid < 4) s[tid] = 0;
  __syncthreads();
  int e0 = blk * EPB + tid * 4;
  u32 c0 = 0, c1 = 0, c2 = 0, c3 = 0;
#pragma unroll
  for (int i = 0; i < 4; ++i) {
    int e = e0 + i;
    if (e < E) {
      int b = eid[e] / N8;
      c0 += (u32)(b == 0) + ((u32)(b == 1) << 16);
      c1 += (u32)(b == 2) + ((u32)(b == 3) << 16);
      c2 += (u32)(b == 4) + ((u32)(b == 5) << 16);
      c3 += (u32)(b == 6) + ((u32)(b == 7) << 16);
    }
  }
  atomicAdd(&s[0], c0); atomicAdd(&s[1], c1);
  atomicAdd(&s[2], c2); atomicAdd(&s[3], c3);
  __syncthreads();
  if (tid == 0) {
#pragma unroll
    for (int b = 0; b < 8; ++b)
      cnt8[b * nblk + blk] = (int)((s[b >> 1] >> ((b & 1) * 16)) & 0xffffu);
  }
}

// ---- exclusive scan of cnt8 (n = 8*nblk) -> bases8; sentinel bases8[n] = E
__global__ void k_scan8(const int* __restrict__ cnt8, int* __restrict__ bases8, int n,
                        int E) {
  __shared__ int s[256];
  int tid = threadIdx.x;
  int ch = (n + 255) / 256;
  int lo = tid * ch, hi = lo + ch < n ? lo + ch : n;
  int sum = 0;
  for (int m = lo; m < hi; ++m) sum += cnt8[m];
  s[tid] = sum;
  __syncthreads();
  for (int st = 1; st < 256; st <<= 1) {
    int add = (tid >= st) ? s[tid - st] : 0;
    __syncthreads();
    s[tid] += add;
    __syncthreads();
  }
  int run = tid ? s[tid - 1] : 0;
  for (int m = lo; m < hi; ++m) {
    bases8[m] = run;
    run += cnt8[m];
  }
  if (tid == 255) bases8[n] = E;
}

// ---- partition edges into 8 dst-range buckets at exact positions (no atomics).
// LDS-reorder per 1024-edge block, then coalesced run writes into bsrc/bseg.
__global__ __launch_bounds__(256) void k_part(const int* __restrict__ ei,
                                              const int* __restrict__ et,
                                              const int* __restrict__ bases8,
                                              int* __restrict__ bsrc,
                                              int* __restrict__ bseg, int E, int N8,
                                              int nblk) {
  __shared__ u32 pscan[256][4];
  __shared__ int lstart[9];
  __shared__ u16 pref[256][8];
  __shared__ int lsrc[EPB];
  __shared__ int lseg[EPB];
  int blk = blockIdx.x, tid = threadIdx.x;
  int base = blk * EPB;
  int nE = E - base; if (nE > EPB) nE = EPB;
  int e0 = base + tid * 4;
  int bk[4], sv[4], gv[4];
  u32 c0 = 0, c1 = 0, c2 = 0, c3 = 0;
#pragma unroll
  for (int i = 0; i < 4; ++i) {
    int e = e0 + i;
    if (e < E) {
      int d = ei[E + e];
      sv[i] = ei[e];
      gv[i] = d * 8 + et[e];
      int b = d / N8;
      bk[i] = b;
      c0 += (u32)(b == 0) + ((u32)(b == 1) << 16);
      c1 += (u32)(b == 2) + ((u32)(b == 3) << 16);
      c2 += (u32)(b == 4) + ((u32)(b == 5) << 16);
      c3 += (u32)(b == 6) + ((u32)(b == 7) << 16);
    } else {
      bk[i] = -1; sv[i] = 0; gv[i] = 0;
    }
  }
  pscan[tid][0] = c0; pscan[tid][1] = c1; pscan[tid][2] = c2; pscan[tid][3] = c3;
  __syncthreads();
  for (int st = 1; st < 256; st <<= 1) {
    u32 a0 = 0, a1 = 0, a2 = 0, a3 = 0;
    if (tid >= st) {
      a0 = pscan[tid - st][0]; a1 = pscan[tid - st][1];
      a2 = pscan[tid - st][2]; a3 = pscan[tid - st][3];
    }
    __syncthreads();
    pscan[tid][0] += a0; pscan[tid][1] += a1; pscan[tid][2] += a2; pscan[tid][3] += a3;
    __syncthreads();
  }
  u32 p0 = pscan[tid][0] - c0, p1 = pscan[tid][1] - c1;
  u32 p2 = pscan[tid][2] - c2, p3 = pscan[tid][3] - c3;
  if (tid == 0) {
    u32 t0 = pscan[255][0], t1 = pscan[255][1], t2 = pscan[255][2], t3 = pscan[255][3];
    int run = 0;
    int tv[8] = {(int)(t0 & 0xffff), (int)(t0 >> 16), (int)(t1 & 0xffff), (int)(t1 >> 16),
                 (int)(t2 & 0xffff), (int)(t2 >> 16), (int)(t3 & 0xffff), (int)(t3 >> 16)};
#pragma unroll
    for (int b = 0; b < 8; ++b) { lstart[b] = run; run += tv[b]; }
    lstart[8] = run;
  }
  __syncthreads();
  pref[tid][0] = (u16)(lstart[0] + (p0 & 0xffff));
  pref[tid][1] = (u16)(lstart[1] + (p0 >> 16));
  pref[tid][2] = (u16)(lstart[2] + (p1 & 0xffff));
  pref[tid][3] = (u16)(lstart[3] + (p1 >> 16));
  pref[tid][4] = (u16)(lstart[4] + (p2 & 0xffff));
  pref[tid][5] = (u16)(lstart[5] + (p2 >> 16));
  pref[tid][6] = (u16)(lstart[6] + (p3 & 0xffff));
  pref[tid][7] = (u16)(lstart[7] + (p3 >> 16));
#pragma unroll
  for (int i = 0; i < 4; ++i) {
    if (bk[i] >= 0) {
      int slot = pref[tid][bk[i]];
      pref[tid][bk[i]] = (u16)(slot + 1);
      lsrc[slot] = sv[i];
      lseg[slot] = gv[i];
    }
  }
  __syncthreads();
  for (int j = tid; j < nE; j += 256) {
    int b = 0;
#pragma unroll
    for (int k = 1; k < 8; ++k) b += (j >= lstart[k]);
    int gpos = bases8[b * nblk + blk] + (j - lstart[b]);
    bsrc[gpos] = lsrc[j];
    bseg[gpos] = lseg[j];
  }
}

// ---- histogram on bucketed segs; bucket = blockIdx&7 -> XCD-local cnt slice
__global__ __launch_bounds__(256) void k_histb(const int* __restrict__ bseg,
                                               const int* __restrict__ bases8,
                                               int* __restrict__ cnt, int nblk) {
  int b = blockIdx.x & 7, chunk = blockIdx.x >> 3;
  int lo = bases8[b * nblk], hi = bases8[(b + 1) * nblk];
  int idx = lo + chunk * EPB + threadIdx.x * 4;
#pragma unroll
  for (int i = 0; i < 4; ++i) {
    int e = idx + i;
    if (e < hi) atomicAdd(&cnt[bseg[e]], 1);
  }
}

__global__ __launch_bounds__(256) void k_scan_reduce(const int* __restrict__ cnt,
                                                     int* __restrict__ blksum, int nseg) {
  __shared__ int s[256];
  int b = blockIdx.x, t = threadIdx.x;
  int base = b * SCAN_CHUNK;
  int sum = 0;
  for (int i = 0; i < 16; ++i) {
    int idx = base + i * 256 + t;
    if (idx < nseg) sum += cnt[idx];
  }
  s[t] = sum;
  __syncthreads();
  for (int st = 128; st > 0; st >>= 1) {
    if (t < st) s[t] += s[t + st];
    __syncthreads();
  }
  if (t == 0) blksum[b] = s[0];
}

__global__ void k_scan_top(int* __restrict__ blksum, int nblk, int* __restrict__ off,
                           int nseg, int E) {
  if (threadIdx.x == 0 && blockIdx.x == 0) {
    int run = 0;
    for (int b = 0; b < nblk; ++b) { int v = blksum[b]; blksum[b] = run; run += v; }
    off[nseg] = E;
  }
}

// writes off AND fill (scatter cursor) -> no separate memcpy
__global__ __launch_bounds__(256) void k_scan_write(const int* __restrict__ cnt,
                                                    const int* __restrict__ blksum,
                                                    int* __restrict__ off,
                                                    int* __restrict__ fill, int nseg) {
  __shared__ int s[256];
  int b = blockIdx.x, t = threadIdx.x;
  int base = b * SCAN_CHUNK + t * 16;
  int v[16];
  int sum = 0;
#pragma unroll
  for (int i = 0; i < 16; ++i) {
    int idx = base + i;
    v[i] = (idx < nseg) ? cnt[idx] : 0;
    sum += v[i];
  }
  s[t] = sum;
  __syncthreads();
  for (int st = 1; st < 256; st <<= 1) {
    int add = (t >= st) ? s[t - st] : 0;
    __syncthreads();
    s[t] += add;
    __syncthreads();
  }
  int run = blksum[b] + s[t] - sum;
#pragma unroll
  for (int i = 0; i < 16; ++i) {
    int idx = base + i;
    if (idx < nseg) { off[idx] = run; fill[idx] = run; }
    run += v[i];
  }
}

// ---- scatter on bucketed edges; bucket = blockIdx&7 -> XCD-local fill/sorted slices
__global__ __launch_bounds__(256) void k_scatterb(const int* __restrict__ bsrc,
                                                  const int* __restrict__ bseg,
                                                  const int* __restrict__ bases8,
                                                  int* __restrict__ fill,
                                                  int* __restrict__ sorted, int nblk) {
  int b = blockIdx.x & 7, chunk = blockIdx.x >> 3;
  int lo = bases8[b * nblk], hi = bases8[(b + 1) * nblk];
  int idx = lo + chunk * EPB + threadIdx.x * 4;
#pragma unroll
  for (int i = 0; i < 4; ++i) {
    int e = idx + i;
    if (e < hi) {
      int pos = atomicAdd(&fill[bseg[e]], 1);
      sorted[pos] = bsrc[e];
    }
  }
}

static __device__ __forceinline__ void add8(float* a, uint4 v) {
  a[0] += bflo(v.x); a[1] += bfhi(v.x);
  a[2] += bflo(v.y); a[3] += bfhi(v.y);
  a[4] += bflo(v.z); a[5] += bfhi(v.z);
  a[6] += bflo(v.w); a[7] += bfhi(v.w);
}

// ---- aggregation: each 8-lane group walks ONE dst's contiguous 8-relation edge span,
// flushing each relation's mean at its boundary (shift register of named regs).
__global__ __launch_bounds__(256) void k_agg(const int* __restrict__ off,
                                             const int* __restrict__ sorted,
                                             const u16* __restrict__ hin,
                                             u16* __restrict__ am, int N, int E) {
  int wave = threadIdx.x >> 6, lane = threadIdx.x & 63;
  int grp = lane >> 3, oct = lane & 7;
  int dst = blockIdx.x * 32 + wave * 8 + grp;
  if (dst >= N) return;
  int4 b0 = *(const int4*)(off + dst * 8);
  int4 b1 = *(const int4*)(off + dst * 8 + 4);
  int je = off[dst * 8 + 8];
  int cs = b0.x;
  int e1 = b0.y, e2 = b0.z, e3 = b0.w, e4 = b1.x, e5 = b1.y, e6 = b1.z, e7 = b1.w, e8 = je;
  u16* ambase = am + (size_t)dst * AMW + oct * 16;
  float a[16];
#pragma unroll
  for (int i = 0; i < 16; ++i) a[i] = 0.f;
  int j = cs;
  int r = 0;
  int lastidx = (E > 0) ? E - 1 : 0;
  while (true) {
    while (r < 8 && j >= e1) {
      int cnt = e1 - cs;
      float norm = (cnt > 0) ? 1.0f / (float)cnt : 0.f;
      uint4 w0, w1;
      w0.x = (u32)f2bf(a[0] * norm) | ((u32)f2bf(a[1] * norm) << 16);
      w0.y = (u32)f2bf(a[2] * norm) | ((u32)f2bf(a[3] * norm) << 16);
      w0.z = (u32)f2bf(a[4] * norm) | ((u32)f2bf(a[5] * norm) << 16);
      w0.w = (u32)f2bf(a[6] * norm) | ((u32)f2bf(a[7] * norm) << 16);
      w1.x = (u32)f2bf(a[8] * norm) | ((u32)f2bf(a[9] * norm) << 16);
      w1.y = (u32)f2bf(a[10] * norm) | ((u32)f2bf(a[11] * norm) << 16);
      w1.z = (u32)f2bf(a[12] * norm) | ((u32)f2bf(a[13] * norm) << 16);
      w1.w = (u32)f2bf(a[14] * norm) | ((u32)f2bf(a[15] * norm) << 16);
      uint4* outp = (uint4*)(ambase + (size_t)r * DD);
      outp[0] = w0;
      outp[1] = w1;
#pragma unroll
      for (int i = 0; i < 16; ++i) a[i] = 0.f;
      cs = e1;
      e1 = e2; e2 = e3; e3 = e4; e4 = e5; e5 = e6; e6 = e7; e7 = e8;
      ++r;
    }
    if (r >= 8) break;
    int j1 = j + 1;
    bool two = (j1 < e1);
    int s0 = sorted[j];
    int s1 = sorted[two ? j1 : lastidx];
    const uint4* p0 = (const uint4*)(hin + (size_t)s0 * DD + oct * 16);
    const uint4* p1 = (const uint4*)(hin + (size_t)s1 * DD + oct * 16);
    uint4 v0 = p0[0], v0b = p0[1];
    uint4 v1 = p1[0], v1b = p1[1];
    if (!two) {
      v1.x = v1.y = v1.z = v1.w = 0u;
      v1b.x = v1b.y = v1b.z = v1b.w = 0u;
    }
    add8(a, v0); add8(a + 8, v0b);
    add8(a, v1); add8(a + 8, v1b);
    j += two ? 2 : 1;
  }
}

// ---- fused GEMM: out[row] = relu( [h[row] | Am[row]] @ Wcat(1152x128) + bias )
// In-place h update safe: each block reads only its own h rows (kt==0) before writing.
template <bool LAST>
__global__ __launch_bounds__(512) void k_gemm(const u16* __restrict__ h,
                                              const u16* __restrict__ am,
                                              const uint4* __restrict__ wt,
                                              const float* __restrict__ bias,
                                              u16* __restrict__ hout,
                                              float* __restrict__ dout, int M) {
  __shared__ uint4 ldsB[2][2048];  // 2 x 32KB
  int tid = threadIdx.x, wave = tid >> 6, lane = tid & 63;
  int rowbase = blockIdx.x * 128 + wave * 16;
  int arow = rowbase + (lane & 15);
  int arc = arow < M ? arow : M - 1;
  int klane = (lane >> 4) << 3;
  f32x4 acc[8];
#pragma unroll
  for (int c = 0; c < 8; ++c) acc[c] = (f32x4)0.f;

#define STAGE(KT, BUF)                                                                   \
  do {                                                                                   \
    const uint4* gsrc = wt + (size_t)(KT) * 2048;                                        \
    _Pragma("unroll") for (int i_ = 0; i_ < 4; ++i_) {                                   \
      int cid_ = i_ * 512 + tid;                                                         \
      __builtin_amdgcn_global_load_lds(                                                  \
          (const __attribute__((address_space(1))) uint4*)(gsrc + cid_),                 \
          (__attribute__((address_space(3))) uint4*)&ldsB[BUF][cid_], 16, 0, 0);         \
    }                                                                                    \
  } while (0)

  STAGE(0, 0);
  for (int kt = 0; kt < NKT; ++kt) {
    int cur = kt & 1;
    __syncthreads();
    if (kt + 1 < NKT) STAGE(kt + 1, cur ^ 1);
    const u16* abase = (kt == 0) ? (h + (size_t)arc * DD)
                                 : (am + (size_t)arc * AMW + (kt - 1) * DD);
#pragma unroll
    for (int kc = 0; kc < 4; ++kc) {
      short8 a = *(const short8*)(abase + kc * 32 + klane);
      int chunk = kc * 4 + (lane >> 4);
#pragma unroll
      for (int c = 0; c < 8; ++c) {
        int col = c * 16 + (lane & 15);
        const short8* bp = (const short8*)&ldsB[cur][col * 16 + (chunk ^ (col & 7))];
        acc[c] = __builtin_amdgcn_mfma_f32_16x16x32_bf16(a, *bp, acc[c], 0, 0, 0);
      }
    }
  }
#undef STAGE

  int crow0 = rowbase + ((lane >> 4) << 2);
  int ccol = lane & 15;
#pragma unroll
  for (int c = 0; c < 8; ++c) {
    int col = c * 16 + ccol;
    float bv = bias[col];
#pragma unroll
    for (int i = 0; i < 4; ++i) {
      int row = crow0 + i;
      if (row < M) {
        float v = fmaxf(acc[c][i] + bv, 0.f);
        if (LAST) dout[(size_t)row * DD + col] = v;
        else hout[(size_t)row * DD + col] = f2bf(v);
      }
    }
  }
}

extern "C" void kernel_launch(void* const* d_in, const int* in_sizes, int n_in,
                              void* d_out, int out_size, void* d_ws, size_t ws_size,
                              hipStream_t stream) {
  const int* x = (const int*)d_in[0];
  const int* ei = (const int*)d_in[1];
  const int* et = (const int*)d_in[2];
  const float* emb = (const float*)d_in[3];
  const float* W = (const float*)d_in[4];
  const float* root = (const float*)d_in[5];
  const float* bias = (const float*)d_in[6];

  const int N = in_sizes[0];
  const int E = in_sizes[2];
  const int NSEG = N * RREL;
  const int N8 = (N + 7) / 8;
  const int nblkE = (E + EPB - 1) / EPB;

  // workspace = round-9 footprint (246.99 MB); bucket arrays overlay the Am region
  size_t o = 0;
  auto al = [&](size_t b) { size_t r = o; o = (o + b + 255) & ~(size_t)255; return r; };
  size_t off_o = al(((size_t)NSEG + 1) * 4);
  size_t cnt_o = al((size_t)NSEG * 4);
  size_t fill_o = al((size_t)NSEG * 4);
  size_t sorted_o = al((size_t)E * 4);
  size_t blk_o = al(4096);
  size_t wt_o = al((size_t)2 * NKT * 2048 * 16);
  size_t h0_o = al((size_t)N * DD * 2);
  size_t am_o = al((size_t)N * AMW * 2);
  (void)am_o;

  char* ws = (char*)d_ws;
  int* off = (int*)(ws + off_o);
  int* cnt = (int*)(ws + cnt_o);
  int* fill = (int*)(ws + fill_o);
  int* sorted = (int*)(ws + sorted_o);
  int* blks = (int*)(ws + blk_o);
  uint4* wt = (uint4*)(ws + wt_o);
  u16* h0 = (u16*)(ws + h0_o);
  u16* am = (u16*)(ws + am_o);
  // overlays inside Am region (used only before k_agg):
  int* bsrc = (int*)(ws + am_o);
  int* bseg = bsrc + E;
  int* cnt8 = bseg + E;
  int* bases8 = cnt8 + 8 * nblkE;
  float* outf = (float*)d_out;

  // ---- prep
  k_convw<<<(2 * NKT * 2048 + 255) / 256, 256, 0, stream>>>(W, root, wt);
  k_gather<<<(N * 16 + 255) / 256, 256, 0, stream>>>(x, emb, h0, N);
  hipMemsetAsync(cnt, 0, (size_t)NSEG * 4, stream);
  k_cnt8<<<nblkE, 256, 0, stream>>>(ei + E, cnt8, E, N8, nblkE);
  k_scan8<<<1, 256, 0, stream>>>(cnt8, bases8, 8 * nblkE, E);
  k_part<<<nblkE, 256, 0, stream>>>(ei, et, bases8, bsrc, bseg, E, N8, nblkE);
  k_histb<<<8 * nblkE, 256, 0, stream>>>(bseg, bases8, cnt, nblkE);
  int nblk = (NSEG + SCAN_CHUNK - 1) / SCAN_CHUNK;
  k_scan_reduce<<<nblk, 256, 0, stream>>>(cnt, blks, NSEG);
  k_scan_top<<<1, 64, 0, stream>>>(blks, nblk, off, NSEG, E);
  k_scan_write<<<nblk, 256, 0, stream>>>(cnt, blks, off, fill, NSEG);
  k_scatterb<<<8 * nblkE, 256, 0, stream>>>(bsrc, bseg, bases8, fill, sorted, nblkE);

  // ---- layers: agg (mean into Am) then fused GEMM (root+rels+bias+relu), h in place
  int gx = (N + 127) / 128;
  int agrid = (N + 31) / 32;
  k_agg<<<agrid, 256, 0, stream>>>(off, sorted, h0, am, N, E);
  k_gemm<false><<<gx, 512, 0, stream>>>(h0, am, wt, bias, h0, nullptr, N);
  k_agg<<<agrid, 256, 0, stream>>>(off, sorted, h0, am, N, E);
  k_gemm<true><<<gx, 512, 0, stream>>>(h0, am, wt + (size_t)NKT * 2048, bias + DD,
                                       nullptr, outf, N);
}